// Round 2
// baseline (1890.700 us; speedup 1.0000x reference)
//
#include <hip/hip_runtime.h>

#define H    32
#define SEQ  1440
#define NT   (SEQ - 1)   // step 1439 is dead code (only h2[:, :1439] is consumed)
#define INP  11
#define TC   64          // timesteps per chunk (x staging + deferred FC)

#define LOG2E 1.44269504f

__device__ __forceinline__ float rcp_fast(float x)  { return __builtin_amdgcn_rcpf(x); }
__device__ __forceinline__ float exp2_fast(float x) { return __builtin_amdgcn_exp2f(x); }
__device__ __forceinline__ float sigm(float a)      { return rcp_fast(1.f + exp2_fast(a * -LOG2E)); }
__device__ __forceinline__ float tanh_f(float x) {
    // tanh(x) = 2*sigmoid(2x) - 1
    return fmaf(2.f, rcp_fast(1.f + exp2_fast(x * (-2.f * LOG2E))), -1.f);
}
__device__ __forceinline__ float bperm(int byteaddr, float v) {
    return __int_as_float(__builtin_amdgcn_ds_bpermute(byteaddr, __float_as_int(v)));
}

// Block = 256 threads (4 waves) = one batch sample.
// Lane l of wave w: j = w*8 + (l>>3) (hidden idx), q = (l>>1)&3 (gate i/f/g/o), kh = l&1 (k-half).
// Thread owns HALF of gate row r=q*32+j: 60 weight regs -> fits 128 VGPR, no spill.
__global__ __launch_bounds__(256, 4)
void lstm_fused_kernel(const float* __restrict__ x,
                       const float* __restrict__ Wih0, const float* __restrict__ Whh0,
                       const float* __restrict__ bih0, const float* __restrict__ bhh0,
                       const float* __restrict__ Wih1, const float* __restrict__ Whh1,
                       const float* __restrict__ bih1, const float* __restrict__ bhh1,
                       const float* __restrict__ fc1w_g, const float* __restrict__ fc1b_g,
                       const float* __restrict__ fc2w_g, const float* __restrict__ fc2b_g,
                       float* __restrict__ out)
{
    __shared__ float h0s[2][H];      // double-buffered layer-0 h
    __shared__ float h1s[2][H];      // double-buffered layer-1 h
    __shared__ float xs[TC][12];     // x chunk [t][i], padded 11->12
    __shared__ float h1c[TC][36];    // layer-1 h history for deferred FC (+pad)

    const int tid = threadIdx.x;
    const int l   = tid & 63;
    const int w   = tid >> 6;
    const int j   = w * 8 + (l >> 3);
    const int q   = (l >> 1) & 3;
    const int kh  = l & 1;
    const int r   = q * 32 + j;
    const int ko  = kh * 16;
    const int b   = blockIdx.x;

    // fold tanh's 2x input scale into the g-gate (q==2) weights/bias
    const float gs = (q == 2) ? 2.f : 1.f;
    const float am = (q == 2) ? 2.f : 1.f;   // act = am*sigmoid + ab
    const float ab = (q == 2) ? -1.f : 0.f;

    float wx[12];
    #pragma unroll
    for (int i = 0; i < INP; ++i) wx[i] = (kh == 0) ? Wih0[r * INP + i] * gs : 0.f;
    wx[11] = 0.f;
    float wh0[16], wi1[16], wh1[16];
    #pragma unroll
    for (int k = 0; k < 16; ++k) {
        wh0[k] = Whh0[r * H + ko + k] * gs;
        wi1[k] = Wih1[r * H + ko + k] * gs;
        wh1[k] = Whh1[r * H + ko + k] * gs;
    }
    const float b0 = (kh == 0) ? (bih0[r] + bhh0[r]) * gs : 0.f;
    const float b1 = (kh == 0) ? (bih1[r] + bhh1[r]) * gs : 0.f;

    // loop-invariant bpermute byte-addresses: gates i,f,g,o of my j (same kh half)
    const int lb = (l & 56) | kh;
    const int ai = (lb | 0) << 2, af = (lb | 2) << 2, ag = (lb | 4) << 2, ao = (lb | 6) << 2;

    if (tid < H) { h0s[0][tid] = 0.f; h1s[0][tid] = 0.f; }
    float c0 = 0.f, c1 = 0.f;

    const float* xb   = x   + (size_t)b * INP * SEQ;   // x[b][i][t], t contiguous
    float*       outb = out + (size_t)b * NT;

    __syncthreads();

    for (int cbase = 0; cbase < NT; cbase += TC) {
        const int clen = min(TC, NT - cbase);

        // ---- stage x[b][:, cbase:cbase+clen] into LDS (coalesced over t) ----
        {
            const int col = tid & 63;
            const int rw  = tid >> 6;
            #pragma unroll
            for (int rb = 0; rb < 12; rb += 4) {
                const int row = rw + rb;
                if (col < clen) {
                    if (row < INP)       xs[col][row] = xb[row * SEQ + cbase + col];
                    else if (row == INP) xs[col][11]  = 0.f;   // pad slot must be clean
                }
            }
        }
        __syncthreads();

        for (int tc = 0; tc < clen; ++tc) {
            const int p = (cbase + tc) & 1;

            // ================= layer 0 =================
            float act;
            {
                const float4* xv = (const float4*)xs[tc];
                const float4* hv = (const float4*)&h0s[p][ko];
                float a0 = b0, a1 = 0.f;
                float4 x0 = xv[0], x1 = xv[1], x2 = xv[2];
                a0 = fmaf(wx[0], x0.x, a0);  a1 = fmaf(wx[1], x0.y, a1);
                a0 = fmaf(wx[2], x0.z, a0);  a1 = fmaf(wx[3], x0.w, a1);
                a0 = fmaf(wx[4], x1.x, a0);  a1 = fmaf(wx[5], x1.y, a1);
                a0 = fmaf(wx[6], x1.z, a0);  a1 = fmaf(wx[7], x1.w, a1);
                a0 = fmaf(wx[8], x2.x, a0);  a1 = fmaf(wx[9], x2.y, a1);
                a0 = fmaf(wx[10], x2.z, a0);
                float4 h0 = hv[0], h1v = hv[1], h2v = hv[2], h3v = hv[3];
                a0 = fmaf(wh0[0],  h0.x,  a0);  a1 = fmaf(wh0[1],  h0.y,  a1);
                a0 = fmaf(wh0[2],  h0.z,  a0);  a1 = fmaf(wh0[3],  h0.w,  a1);
                a0 = fmaf(wh0[4],  h1v.x, a0);  a1 = fmaf(wh0[5],  h1v.y, a1);
                a0 = fmaf(wh0[6],  h1v.z, a0);  a1 = fmaf(wh0[7],  h1v.w, a1);
                a0 = fmaf(wh0[8],  h2v.x, a0);  a1 = fmaf(wh0[9],  h2v.y, a1);
                a0 = fmaf(wh0[10], h2v.z, a0);  a1 = fmaf(wh0[11], h2v.w, a1);
                a0 = fmaf(wh0[12], h3v.x, a0);  a1 = fmaf(wh0[13], h3v.y, a1);
                a0 = fmaf(wh0[14], h3v.z, a0);  a1 = fmaf(wh0[15], h3v.w, a1);
                float a = a0 + a1;
                a += __shfl_xor(a, 1);           // combine k-halves
                act = fmaf(am, sigm(a), ab);
            }
            {
                float gi = bperm(ai, act), gf = bperm(af, act);
                float gg = bperm(ag, act), go = bperm(ao, act);
                c0 = fmaf(gf, c0, gi * gg);      // redundant in 8 lanes of j-group
                float hn = go * tanh_f(c0);
                if ((l & 7) == 0) h0s[p ^ 1][j] = hn;
            }
            __syncthreads();   // new h0 visible to all waves

            // ================= layer 1 =================
            {
                const float4* iv = (const float4*)&h0s[p ^ 1][ko];
                const float4* hv = (const float4*)&h1s[p][ko];
                float a0 = b1, a1 = 0.f, a2 = 0.f, a3 = 0.f;
                float4 i0 = iv[0], i1 = iv[1], i2 = iv[2], i3 = iv[3];
                float4 h0v = hv[0], h1v = hv[1], h2v = hv[2], h3v = hv[3];
                a0 = fmaf(wi1[0],  i0.x,  a0);  a1 = fmaf(wi1[1],  i0.y,  a1);
                a2 = fmaf(wi1[2],  i0.z,  a2);  a3 = fmaf(wi1[3],  i0.w,  a3);
                a0 = fmaf(wi1[4],  i1.x,  a0);  a1 = fmaf(wi1[5],  i1.y,  a1);
                a2 = fmaf(wi1[6],  i1.z,  a2);  a3 = fmaf(wi1[7],  i1.w,  a3);
                a0 = fmaf(wi1[8],  i2.x,  a0);  a1 = fmaf(wi1[9],  i2.y,  a1);
                a2 = fmaf(wi1[10], i2.z,  a2);  a3 = fmaf(wi1[11], i2.w,  a3);
                a0 = fmaf(wi1[12], i3.x,  a0);  a1 = fmaf(wi1[13], i3.y,  a1);
                a2 = fmaf(wi1[14], i3.z,  a2);  a3 = fmaf(wi1[15], i3.w,  a3);
                a0 = fmaf(wh1[0],  h0v.x, a0);  a1 = fmaf(wh1[1],  h0v.y, a1);
                a2 = fmaf(wh1[2],  h0v.z, a2);  a3 = fmaf(wh1[3],  h0v.w, a3);
                a0 = fmaf(wh1[4],  h1v.x, a0);  a1 = fmaf(wh1[5],  h1v.y, a1);
                a2 = fmaf(wh1[6],  h1v.z, a2);  a3 = fmaf(wh1[7],  h1v.w, a3);
                a0 = fmaf(wh1[8],  h2v.x, a0);  a1 = fmaf(wh1[9],  h2v.y, a1);
                a2 = fmaf(wh1[10], h2v.z, a2);  a3 = fmaf(wh1[11], h2v.w, a3);
                a0 = fmaf(wh1[12], h3v.x, a0);  a1 = fmaf(wh1[13], h3v.y, a1);
                a2 = fmaf(wh1[14], h3v.z, a2);  a3 = fmaf(wh1[15], h3v.w, a3);
                float a = (a0 + a1) + (a2 + a3);
                a += __shfl_xor(a, 1);
                act = fmaf(am, sigm(a), ab);
            }
            {
                float gi = bperm(ai, act), gf = bperm(af, act);
                float gg = bperm(ag, act), go = bperm(ao, act);
                c1 = fmaf(gf, c1, gi * gg);
                float hn = go * tanh_f(c1);
                if ((l & 7) == 0) { h1s[p ^ 1][j] = hn; h1c[tc][j] = hn; }
            }
            __syncthreads();   // h1/h1c visible; h-buffer reads done before overwrite
        }

        // ---- deferred FC head: unit u (k-half kh2) x 16 timesteps in parallel ----
        {
            const int u   = tid & 15;
            const int kh2 = (tid >> 4) & 1;
            const int ti  = tid >> 5;          // 0..7
            const int ko2 = kh2 * 16;
            float fw[16];                       // loaded per chunk -> not live in main loop
            #pragma unroll
            for (int k = 0; k < 16; ++k) fw[k] = fc1w_g[u * H + ko2 + k];
            const float fb  = fc1b_g[u];
            const float f2w = fc2w_g[u];
            const float f2b = fc2b_g[0];
            #pragma unroll
            for (int rep = 0; rep < 8; ++rep) {
                const int t2 = ti + 8 * rep;
                if (t2 < clen) {
                    const float4* hv = (const float4*)&h1c[t2][ko2];
                    float a0 = 0.f, a1 = 0.f;
                    float4 v0 = hv[0], v1 = hv[1], v2 = hv[2], v3 = hv[3];
                    a0 = fmaf(fw[0],  v0.x, a0);  a1 = fmaf(fw[1],  v0.y, a1);
                    a0 = fmaf(fw[2],  v0.z, a0);  a1 = fmaf(fw[3],  v0.w, a1);
                    a0 = fmaf(fw[4],  v1.x, a0);  a1 = fmaf(fw[5],  v1.y, a1);
                    a0 = fmaf(fw[6],  v1.z, a0);  a1 = fmaf(fw[7],  v1.w, a1);
                    a0 = fmaf(fw[8],  v2.x, a0);  a1 = fmaf(fw[9],  v2.y, a1);
                    a0 = fmaf(fw[10], v2.z, a0);  a1 = fmaf(fw[11], v2.w, a1);
                    a0 = fmaf(fw[12], v3.x, a0);  a1 = fmaf(fw[13], v3.y, a1);
                    a0 = fmaf(fw[14], v3.z, a0);  a1 = fmaf(fw[15], v3.w, a1);
                    float y = a0 + a1;
                    y += __shfl_xor(y, 16);                      // combine k-halves
                    float z = tanh_f(y + fb) * f2w;
                    z += __shfl_xor(z, 1);  z += __shfl_xor(z, 2);
                    z += __shfl_xor(z, 4);  z += __shfl_xor(z, 8);
                    if ((tid & 31) == 0) outb[cbase + t2] = z + f2b;
                }
            }
        }
        // no trailing barrier needed: next chunk's staging barrier orders h1c reuse
    }
}

extern "C" void kernel_launch(void* const* d_in, const int* in_sizes, int n_in,
                              void* d_out, int out_size, void* d_ws, size_t ws_size,
                              hipStream_t stream)
{
    const float* x    = (const float*)d_in[0];
    const float* Wih0 = (const float*)d_in[1];
    const float* Whh0 = (const float*)d_in[2];
    const float* bih0 = (const float*)d_in[3];
    const float* bhh0 = (const float*)d_in[4];
    const float* Wih1 = (const float*)d_in[5];
    const float* Whh1 = (const float*)d_in[6];
    const float* bih1 = (const float*)d_in[7];
    const float* bhh1 = (const float*)d_in[8];
    const float* fc1w = (const float*)d_in[9];
    const float* fc1b = (const float*)d_in[10];
    const float* fc2w = (const float*)d_in[11];
    const float* fc2b = (const float*)d_in[12];
    float* out = (float*)d_out;

    const int B = in_sizes[0] / (INP * SEQ);   // 1024
    dim3 grid(B), block(256);
    hipLaunchKernelGGL(lstm_fused_kernel, grid, block, 0, stream,
                       x, Wih0, Whh0, bih0, bhh0, Wih1, Whh1, bih1, bhh1,
                       fc1w, fc1b, fc2w, fc2b, out);
}

// Round 3
// 1261.614 us; speedup vs baseline: 1.4986x; 1.4986x over previous
//
#include <hip/hip_runtime.h>

#define H    32
#define SEQ  1440
#define NT   (SEQ - 1)   // step 1439 is dead code (only h2[:, :1439] is consumed)
#define INP  11
#define TC   64          // timesteps per chunk (x staging + deferred FC)

#define LOG2E 1.44269504f

__device__ __forceinline__ float rcp_fast(float x)  { return __builtin_amdgcn_rcpf(x); }
__device__ __forceinline__ float exp2_fast(float x) { return __builtin_amdgcn_exp2f(x); }
__device__ __forceinline__ float tanh_f(float x) {
    // tanh(x) = 2/(1+exp2(-2*log2e*x)) - 1
    return fmaf(2.f, rcp_fast(1.f + exp2_fast(x * (-2.f * LOG2E))), -1.f);
}

// Block = 128 threads (2 waves) = one batch sample.
// Thread (wave wv, lane l): gate q = l>>4 (i/f/g/o), hidden jj = wv*16 + (l&15).
// Weight row r = q*32+jj held in registers, pre-scaled by log2e (and 2x for the
// g-gate) so the activation needs no input multiply:
//   act = am * rcp(1 + exp2(-a)) + ab   (am,ab = 2,-1 for g-gate; 1,0 otherwise)
// amdgpu_waves_per_eu(2,2) pins the allocator at 2 waves/SIMD (= the grid-imposed
// occupancy anyway) -> 256-VGPR budget -> ~170-reg weight set stays resident.
__global__
__attribute__((amdgpu_flat_work_group_size(128, 128)))
__attribute__((amdgpu_waves_per_eu(2, 2)))
void lstm_fused_kernel(const float* __restrict__ x,
                       const float* __restrict__ Wih0, const float* __restrict__ Whh0,
                       const float* __restrict__ bih0, const float* __restrict__ bhh0,
                       const float* __restrict__ Wih1, const float* __restrict__ Whh1,
                       const float* __restrict__ bih1, const float* __restrict__ bhh1,
                       const float* __restrict__ fc1w_g, const float* __restrict__ fc1b_g,
                       const float* __restrict__ fc2w_g, const float* __restrict__ fc2b_g,
                       float* __restrict__ out)
{
    __shared__ float h0s[2][H];      // double-buffered layer-0 h
    __shared__ float h1s[2][H];      // double-buffered layer-1 h
    __shared__ float xs[TC][12];     // x chunk [t][i], padded 11->12
    __shared__ float h1c[TC][36];    // layer-1 h history for deferred FC (+pad)

    const int tid  = threadIdx.x;
    const int lane = tid & 63;
    const int wv   = tid >> 6;
    const int m    = lane & 15;
    const int q    = lane >> 4;
    const int jj   = wv * 16 + m;
    const int r    = q * 32 + jj;
    const int b    = blockIdx.x;

    const float gsl = ((q == 2) ? 2.f : 1.f) * LOG2E;   // fold tanh 2x + log2e
    const float am  = (q == 2) ? 2.f : 1.f;
    const float ab  = (q == 2) ? -1.f : 0.f;

    // ---- weights -> registers (pre-scaled), resident for the whole kernel ----
    float wx[12];
    #pragma unroll
    for (int i = 0; i < INP; ++i) wx[i] = Wih0[r * INP + i] * gsl;
    wx[11] = 0.f;
    float wh0[H], wi1[H], wh1[H];
    #pragma unroll
    for (int k = 0; k < H; ++k) {
        wh0[k] = Whh0[r * H + k] * gsl;
        wi1[k] = Wih1[r * H + k] * gsl;
        wh1[k] = Whh1[r * H + k] * gsl;
    }
    const float bs0 = (bih0[r] + bhh0[r]) * gsl;
    const float bs1 = (bih1[r] + bhh1[r]) * gsl;

    if (tid < H) { h0s[0][tid] = 0.f; h1s[0][tid] = 0.f; }
    float c0 = 0.f, c1 = 0.f;

    const float* xb   = x   + (size_t)b * INP * SEQ;   // x[b][i][t], t contiguous
    float*       outb = out + (size_t)b * NT;

    __syncthreads();

    for (int cbase = 0; cbase < NT; cbase += TC) {
        const int clen = min(TC, NT - cbase);

        // ---- stage x[b][:, cbase:cbase+clen] into LDS (coalesced over t) ----
        {
            const int col = tid & 63;
            const int rw  = tid >> 6;
            #pragma unroll
            for (int ib = 0; ib < 12; ib += 2) {
                const int row = ib + rw;
                if (col < clen)
                    xs[col][row] = (row < INP) ? xb[row * SEQ + cbase + col] : 0.f;
            }
        }
        __syncthreads();

        for (int tc = 0; tc < clen; ++tc) {
            const int p = (cbase + tc) & 1;   // h double-buffer parity

            // ================= layer 0 =================
            float act;
            {
                const float4* xv = (const float4*)xs[tc];
                const float4* hv = (const float4*)h0s[p];
                float a0 = bs0, a1 = 0.f;
                float4 x0 = xv[0], x1 = xv[1], x2 = xv[2];
                a0 = fmaf(wx[0],  x0.x, a0);  a1 = fmaf(wx[1],  x0.y, a1);
                a0 = fmaf(wx[2],  x0.z, a0);  a1 = fmaf(wx[3],  x0.w, a1);
                a0 = fmaf(wx[4],  x1.x, a0);  a1 = fmaf(wx[5],  x1.y, a1);
                a0 = fmaf(wx[6],  x1.z, a0);  a1 = fmaf(wx[7],  x1.w, a1);
                a0 = fmaf(wx[8],  x2.x, a0);  a1 = fmaf(wx[9],  x2.y, a1);
                a0 = fmaf(wx[10], x2.z, a0);
                #pragma unroll
                for (int kk = 0; kk < 4; ++kk) {
                    float4 ha = hv[kk], hb = hv[kk + 4];
                    a0 = fmaf(wh0[4*kk+0],    ha.x, a0);
                    a1 = fmaf(wh0[4*kk+1],    ha.y, a1);
                    a0 = fmaf(wh0[4*kk+2],    ha.z, a0);
                    a1 = fmaf(wh0[4*kk+3],    ha.w, a1);
                    a0 = fmaf(wh0[16+4*kk+0], hb.x, a0);
                    a1 = fmaf(wh0[16+4*kk+1], hb.y, a1);
                    a0 = fmaf(wh0[16+4*kk+2], hb.z, a0);
                    a1 = fmaf(wh0[16+4*kk+3], hb.w, a1);
                }
                float a = a0 + a1;
                act = fmaf(am, rcp_fast(1.f + exp2_fast(-a)), ab);
            }
            // gates i,f,g,o live at lanes l, l+16, l+32, l+48 of this wave
            float gf = __shfl_xor(act, 16);
            float gg = __shfl_xor(act, 32);
            float go = __shfl_xor(act, 48);
            if (q == 0) {
                c0 = fmaf(gf, c0, act * gg);
                h0s[p ^ 1][jj] = go * tanh_f(c0);
            }
            __syncthreads();   // new h0 visible to both waves

            // ================= layer 1 =================
            {
                const float4* hav = (const float4*)h0s[p ^ 1];  // input = new h0
                const float4* hbv = (const float4*)h1s[p];      // recurrent = old h1
                float a0 = bs1, a1 = 0.f, a2 = 0.f, a3 = 0.f;
                #pragma unroll
                for (int kk = 0; kk < 4; ++kk) {
                    float4 ha = hav[kk], ha2 = hav[kk + 4];
                    float4 hb = hbv[kk], hb2 = hbv[kk + 4];
                    a0 = fmaf(wi1[4*kk+0],    ha.x,  a0); a1 = fmaf(wi1[4*kk+1],    ha.y,  a1);
                    a2 = fmaf(wi1[4*kk+2],    ha.z,  a2); a3 = fmaf(wi1[4*kk+3],    ha.w,  a3);
                    a0 = fmaf(wi1[16+4*kk+0], ha2.x, a0); a1 = fmaf(wi1[16+4*kk+1], ha2.y, a1);
                    a2 = fmaf(wi1[16+4*kk+2], ha2.z, a2); a3 = fmaf(wi1[16+4*kk+3], ha2.w, a3);
                    a0 = fmaf(wh1[4*kk+0],    hb.x,  a0); a1 = fmaf(wh1[4*kk+1],    hb.y,  a1);
                    a2 = fmaf(wh1[4*kk+2],    hb.z,  a2); a3 = fmaf(wh1[4*kk+3],    hb.w,  a3);
                    a0 = fmaf(wh1[16+4*kk+0], hb2.x, a0); a1 = fmaf(wh1[16+4*kk+1], hb2.y, a1);
                    a2 = fmaf(wh1[16+4*kk+2], hb2.z, a2); a3 = fmaf(wh1[16+4*kk+3], hb2.w, a3);
                }
                float a = (a0 + a1) + (a2 + a3);
                act = fmaf(am, rcp_fast(1.f + exp2_fast(-a)), ab);
            }
            gf = __shfl_xor(act, 16);
            gg = __shfl_xor(act, 32);
            go = __shfl_xor(act, 48);
            if (q == 0) {
                c1 = fmaf(gf, c1, act * gg);
                float hn = go * tanh_f(c1);
                h1s[p ^ 1][jj] = hn;
                h1c[tc][jj]    = hn;   // history for deferred FC
            }
            __syncthreads();   // h1/h1c visible
        }

        // ---- deferred FC head: 16 units x clen steps, all 128 threads ----
        // FC weights are chunk-local: NOT live across the main step loop.
        {
            const int u = tid & 15;
            float fcw[H];
            #pragma unroll
            for (int k = 0; k < H; ++k) fcw[k] = fc1w_g[u * H + k];
            const float fcb = fc1b_g[u];
            const float f2w = fc2w_g[u];
            const float f2b = fc2b_g[0];
            #pragma unroll
            for (int rep = 0; rep < 8; ++rep) {
                const int tcl = (tid >> 4) + 8 * rep;   // uniform within 16-lane group
                if (tcl < clen) {
                    const float4* hv = (const float4*)h1c[tcl];
                    float a0 = fcb, a1 = 0.f;
                    #pragma unroll
                    for (int kk = 0; kk < 4; ++kk) {
                        float4 ha = hv[kk], hb = hv[kk + 4];
                        a0 = fmaf(fcw[4*kk+0],    ha.x, a0); a1 = fmaf(fcw[4*kk+1],    ha.y, a1);
                        a0 = fmaf(fcw[4*kk+2],    ha.z, a0); a1 = fmaf(fcw[4*kk+3],    ha.w, a1);
                        a0 = fmaf(fcw[16+4*kk+0], hb.x, a0); a1 = fmaf(fcw[16+4*kk+1], hb.y, a1);
                        a0 = fmaf(fcw[16+4*kk+2], hb.z, a0); a1 = fmaf(fcw[16+4*kk+3], hb.w, a1);
                    }
                    float yv = tanh_f(a0 + a1) * f2w;
                    yv += __shfl_xor(yv, 1);
                    yv += __shfl_xor(yv, 2);
                    yv += __shfl_xor(yv, 4);
                    yv += __shfl_xor(yv, 8);
                    if (u == 0) outb[cbase + tcl] = yv + f2b;
                }
            }
        }
        __syncthreads();   // h1c reads done before next chunk's steps overwrite
    }
}

extern "C" void kernel_launch(void* const* d_in, const int* in_sizes, int n_in,
                              void* d_out, int out_size, void* d_ws, size_t ws_size,
                              hipStream_t stream)
{
    const float* x    = (const float*)d_in[0];
    const float* Wih0 = (const float*)d_in[1];
    const float* Whh0 = (const float*)d_in[2];
    const float* bih0 = (const float*)d_in[3];
    const float* bhh0 = (const float*)d_in[4];
    const float* Wih1 = (const float*)d_in[5];
    const float* Whh1 = (const float*)d_in[6];
    const float* bih1 = (const float*)d_in[7];
    const float* bhh1 = (const float*)d_in[8];
    const float* fc1w = (const float*)d_in[9];
    const float* fc1b = (const float*)d_in[10];
    const float* fc2w = (const float*)d_in[11];
    const float* fc2b = (const float*)d_in[12];
    float* out = (float*)d_out;

    const int B = in_sizes[0] / (INP * SEQ);   // 1024
    dim3 grid(B), block(128);
    hipLaunchKernelGGL(lstm_fused_kernel, grid, block, 0, stream,
                       x, Wih0, Whh0, bih0, bhh0, Wih1, Whh1, bih1, bhh1,
                       fc1w, fc1b, fc2w, fc2b, out);
}